// Round 3
// baseline (22153.418 us; speedup 1.0000x reference)
//
#include <hip/hip_runtime.h>
#include <cmath>

#define SS 512
#define BB 64
#define II 256
#define HH 1024
#define BH (BB*HH)   // 65536

typedef _Float16 half8 __attribute__((ext_vector_type(8)));
typedef float    floatx4 __attribute__((ext_vector_type(4)));

// ---------------------------------------------------------------------------
// prep_misc: convert X fp32->fp16, zero h buffer 0 (hi+lo), zero flags
// grid 4096 x 256 = 1,048,576 threads
// ---------------------------------------------------------------------------
__global__ void prep_misc(const float* __restrict__ X, _Float16* __restrict__ X16,
                          _Float16* __restrict__ h_hi, _Float16* __restrict__ h_lo,
                          unsigned* __restrict__ flags) {
    const int tid = blockIdx.x * 256 + threadIdx.x;
    const size_t base = (size_t)tid * 8;   // 8 elems/thread covers 8,388,608 exactly
    #pragma unroll
    for (int j = 0; j < 8; ++j) X16[base + j] = (_Float16)X[base + j];
    if (tid < 49152) {
        ((unsigned long long*)h_hi)[tid] = 0ULL;
        ((unsigned long long*)h_lo)[tid] = 0ULL;
    }
    if (tid < 256) flags[tid] = 0u;
}

// ---------------------------------------------------------------------------
// prep_bpack: pack per-WG weight slices into MFMA B-fragment order, fp16.
// WG w (0..95) = layer (w>>5) x n-group g (w&31, 32 cols = 2 tiles of 16).
// Frag slot (c, ks): c=col-tile 0..1, ks=global k-step 0..63 (32 K each).
//   layer0:  ks 0..7 = Wxh, ks 8..39 = Whh (rest unused)
//   layer>=1: ks 0..31 = U_{l-1}, ks 32..63 = W_{l-1}
// B-frag layout (16x16x32 f16): lane holds B[k=(lane>>4)*8+j][n=lane&15].
// One thread per (w, c, ks, lane): 96*2*64*64 = 786,432 -> 3072 x 256.
// ---------------------------------------------------------------------------
__global__ void prep_bpack(const float* __restrict__ Wxh, const float* __restrict__ Whh,
                           const float* __restrict__ Wl,  const float* __restrict__ Ul,
                           _Float16* __restrict__ Bpack) {
    const int tid  = blockIdx.x * 256 + threadIdx.x;
    const int w    = tid >> 13;         // 0..95
    const int r    = tid & 8191;
    const int c    = r >> 12;           // 0..1
    const int ks   = (r >> 6) & 63;     // 0..63
    const int lane = r & 63;
    const int layer = w >> 5;
    const int g     = w & 31;
    const int n  = g * 32 + c * 16 + (lane & 15);
    const int kq = (lane >> 4) * 8;
    const float* src;
    int k;
    if (layer == 0) {
        if (ks >= 40) return;
        if (ks < 8) { src = Wxh; k = ks * 32 + kq; }
        else        { src = Whh; k = (ks - 8) * 32 + kq; }
    } else {
        const int li = layer - 1;
        if (ks < 32) { src = Ul + (size_t)li * HH * HH; k = ks * 32 + kq; }
        else         { src = Wl + (size_t)li * HH * HH; k = (ks - 32) * 32 + kq; }
    }
    _Float16* dst = Bpack + (size_t)w * 65536 + (size_t)(c * 64 + ks) * 512 + (size_t)lane * 8;
    #pragma unroll
    for (int j = 0; j < 8; ++j) dst[j] = (_Float16)src[(size_t)(k + j) * HH + n];
}

// ---------------------------------------------------------------------------
// Persistent RNN kernel. 96 WGs x 512 threads (8 waves), all co-resident.
// Wave = (c = wave>>2: col-tile of 16) x (kh = wave&3: K-quarter).
// Each wave: all 64 batch rows (4 A-frags), 16 cols, its K-quarter, weights
// in registers (regB, 64 VGPRs). K-quarter partials reduced via global red
// (L2-served). One single-hop flag barrier per step.
// ---------------------------------------------------------------------------
__global__ __launch_bounds__(512, 2) void rnn_persist(
        const _Float16* __restrict__ X16,
        const _Float16* __restrict__ Bpack,
        _Float16* __restrict__ h_hi,   // [2][3][B][H]
        _Float16* __restrict__ h_lo,
        float* __restrict__ red,       // [96][2c][3kh][4r][64 lanes][4]
        unsigned* __restrict__ flags,  // [96] monotonic step counters
        const float* __restrict__ b_h,
        const float* __restrict__ b_layers,
        float* __restrict__ out) {

    const int wgid  = blockIdx.x;
    const int layer = wgid >> 5;
    const int g     = wgid & 31;
    const int tid   = threadIdx.x;
    const int wave  = tid >> 6;
    const int lane  = tid & 63;
    const int c     = wave >> 2;        // col-tile 0..1
    const int kh    = wave & 3;         // K-quarter 0..3
    const int lm    = lane & 15;
    const int kq    = (lane >> 4) * 8;
    const int n     = g * 32 + c * 16 + lm;

    // ---- load this wave's weight fragments into registers (once) ----
    half8 regB[16];
    {
        const _Float16* bp = Bpack + (size_t)wgid * 65536 + (size_t)c * 64 * 512
                                   + (size_t)lane * 8;
        if (layer == 0) {
            #pragma unroll
            for (int j = 0; j < 2; ++j)
                regB[j] = *(const half8*)(bp + (size_t)(kh * 2 + j) * 512);
            #pragma unroll
            for (int j = 0; j < 8; ++j)
                regB[2 + j] = *(const half8*)(bp + (size_t)(8 + kh * 8 + j) * 512);
        } else {
            #pragma unroll
            for (int j = 0; j < 8; ++j)
                regB[j] = *(const half8*)(bp + (size_t)(kh * 8 + j) * 512);
            #pragma unroll
            for (int j = 0; j < 8; ++j)
                regB[8 + j] = *(const half8*)(bp + (size_t)(32 + kh * 8 + j) * 512);
        }
    }

    const float bv = (layer == 0) ? b_h[n] : b_layers[(size_t)(layer - 1) * HH + n];

    for (int t = 0; t < SS; ++t) {
        const int rb = t & 1;
        const _Float16* hi = h_hi + (size_t)rb * 3 * BH;
        const _Float16* lo = h_lo + (size_t)rb * 3 * BH;
        _Float16* nhi = h_hi + (size_t)(rb ^ 1) * 3 * BH;
        _Float16* nlo = h_lo + (size_t)(rb ^ 1) * 3 * BH;

        floatx4 aH[4], aL[4];
        #pragma unroll
        for (int r2 = 0; r2 < 4; ++r2) {
            aH[r2] = (floatx4){0.f, 0.f, 0.f, 0.f};
            aL[r2] = (floatx4){0.f, 0.f, 0.f, 0.f};
        }

        auto seg = [&](const _Float16* Ah, const _Float16* Al, int ksg) {
            const int koff = kh * 256 + kq;
            #pragma unroll
            for (int i = 0; i < 8; ++i) {
                const half8 b = regB[ksg + i];
                #pragma unroll
                for (int r2 = 0; r2 < 4; ++r2) {
                    const size_t ro = (size_t)(r2 * 16 + lm) * HH + koff + i * 32;
                    aH[r2] = __builtin_amdgcn_mfma_f32_16x16x32_f16(
                                 *(const half8*)(Ah + ro), b, aH[r2], 0, 0, 0);
                    aL[r2] = __builtin_amdgcn_mfma_f32_16x16x32_f16(
                                 *(const half8*)(Al + ro), b, aL[r2], 0, 0, 0);
                }
            }
        };

        if (layer == 0) {
            const _Float16* Xt = X16 + (size_t)t * BB * II;
            const int koffX = kh * 64 + kq;
            #pragma unroll
            for (int i = 0; i < 2; ++i) {
                const half8 b = regB[i];
                #pragma unroll
                for (int r2 = 0; r2 < 4; ++r2) {
                    const size_t ro = (size_t)(r2 * 16 + lm) * II + koffX + i * 32;
                    aH[r2] = __builtin_amdgcn_mfma_f32_16x16x32_f16(
                                 *(const half8*)(Xt + ro), b, aH[r2], 0, 0, 0);
                }
            }
            seg(hi + 0 * BH, lo + 0 * BH, 2);
        } else {
            seg(hi + (size_t)layer * BH,       lo + (size_t)layer * BH,       0);
            seg(hi + (size_t)(layer - 1) * BH, lo + (size_t)(layer - 1) * BH, 8);
        }

        // ---- K-quarter reduction via per-WG global scratch (L2-hit) ----
        if (kh != 0) {
            float* rp = red + (size_t)wgid * 6144
                            + (size_t)((c * 3 + (kh - 1)) * 4) * 256 + (size_t)lane * 4;
            #pragma unroll
            for (int r2 = 0; r2 < 4; ++r2)
                *(floatx4*)(rp + r2 * 256) = aH[r2] + aL[r2];
        }
        __syncthreads();

        if (kh == 0) {
            const float* rp = red + (size_t)wgid * 6144
                                  + (size_t)(c * 3 * 4) * 256 + (size_t)lane * 4;
            #pragma unroll
            for (int r2 = 0; r2 < 4; ++r2) {
                floatx4 s = aH[r2] + aL[r2];
                #pragma unroll
                for (int kk = 0; kk < 3; ++kk)
                    s += *(const floatx4*)(rp + (kk * 4 + r2) * 256);
                const int mb = r2 * 16 + (lane >> 4) * 4;
                #pragma unroll
                for (int rr = 0; rr < 4; ++rr) {
                    const float v = tanhf(s[rr] + bv);
                    const int m = mb + rr;
                    const size_t hoff = (size_t)layer * BH + (size_t)m * HH + n;
                    const _Float16 vh = (_Float16)v;
                    __builtin_nontemporal_store(vh, nhi + hoff);
                    __builtin_nontemporal_store((_Float16)(v - (float)vh), nlo + hoff);
                    if (layer == 2)
                        __builtin_nontemporal_store(v, out + (size_t)t * BH + (size_t)m * HH + n);
                    if (t == SS - 1)
                        __builtin_nontemporal_store(v, out + (size_t)SS * BH
                                       + (size_t)layer * BH + (size_t)m * HH + n);
                }
            }
        }

        // ---- single-hop device barrier ----
        __syncthreads();   // drains all waves' stores (vmcnt) before flagging
        if (tid == 0)
            __hip_atomic_store(&flags[wgid], (unsigned)(t + 1),
                               __ATOMIC_RELEASE, __HIP_MEMORY_SCOPE_AGENT);
        if (tid < 96) {
            while (__hip_atomic_load(&flags[tid], __ATOMIC_RELAXED,
                                     __HIP_MEMORY_SCOPE_AGENT) < (unsigned)(t + 1))
                __builtin_amdgcn_s_sleep(1);
        }
        __syncthreads();
        __builtin_amdgcn_fence(__ATOMIC_ACQUIRE, "agent");
    }
}

// ---------------------------------------------------------------------------
extern "C" void kernel_launch(void* const* d_in, const int* in_sizes, int n_in,
                              void* d_out, int out_size, void* d_ws, size_t ws_size,
                              hipStream_t stream) {
    (void)in_sizes; (void)n_in; (void)out_size; (void)ws_size;
    const float* X   = (const float*)d_in[0];
    const float* Wxh = (const float*)d_in[1];
    const float* Whh = (const float*)d_in[2];
    const float* bh  = (const float*)d_in[3];
    const float* Wl  = (const float*)d_in[4];
    const float* Ul  = (const float*)d_in[5];
    const float* bl  = (const float*)d_in[6];
    float* out = (float*)d_out;

    char* ws = (char*)d_ws;
    _Float16* X16   = (_Float16*)(ws);                       // 16,777,216 B
    _Float16* Bpack = (_Float16*)(ws + 16777216);            // 12,582,912 B
    _Float16* h_hi  = (_Float16*)(ws + 29360128);            //    786,432 B
    _Float16* h_lo  = (_Float16*)(ws + 30146560);            //    786,432 B
    float*    red   = (float*)   (ws + 30932992);            //  2,359,296 B
    unsigned* flags = (unsigned*)(ws + 33292288);            //      1,024 B

    hipLaunchKernelGGL(prep_misc,  dim3(4096), dim3(256), 0, stream, X, X16, h_hi, h_lo, flags);
    hipLaunchKernelGGL(prep_bpack, dim3(3072), dim3(256), 0, stream, Wxh, Whh, Wl, Ul, Bpack);
    hipLaunchKernelGGL(rnn_persist, dim3(96), dim3(512), 0, stream,
                       X16, Bpack, h_hi, h_lo, red, flags, bh, bl, out);
}